// Round 1
// baseline (1251.735 us; speedup 1.0000x reference)
//
#include <hip/hip_runtime.h>
#include <math.h>

#define N_TS 4096
#define SEQ  168
#define HOR  24
#define T_ALL 192
#define F_INP 32
#define EMB  32
#define HID  64

__device__ __forceinline__ float fexp(float x)  { return __expf(x); }
__device__ __forceinline__ float frcp(float x)  { return __builtin_amdgcn_rcpf(x); }
__device__ __forceinline__ float sigm(float x)  { return frcp(1.0f + fexp(-x)); }
__device__ __forceinline__ float tanh_(float x) { return 1.0f - 2.0f * frcp(1.0f + fexp(2.0f * x)); }
__device__ __forceinline__ float softplus_(float x) { return (x > 15.0f) ? x : __logf(1.0f + fexp(x)); }

// ---------------------------------------------------------------------------
// Kernel A: all teacher-forced cells (n, t) for t in [0, 168). Fully parallel.
// One thread per cell. f-gate skipped (c0 == 0).
// ---------------------------------------------------------------------------
__global__ __launch_bounds__(128) void cellsA(
    const float* __restrict__ X,        // (N, 168, 32)
    const float* __restrict__ y,        // (N, 168)
    const float* __restrict__ W_embed,  // (32)
    const float* __restrict__ b_embed,  // (32)
    const float* __restrict__ W_ih,     // (2, 256, 64)
    const float* __restrict__ b_ih,     // (2, 256)
    const float* __restrict__ b_hh,     // (2, 256)
    const float* __restrict__ W_mu,     // (64)
    const float* __restrict__ b_mu,     // (1)
    const float* __restrict__ W_sigma,  // (64)
    const float* __restrict__ b_sigma,  // (1)
    float* __restrict__ out,            // ypred(4096,24) | mu(4096,192) | sigma(4096,192)
    float* __restrict__ lik167)         // (N) workspace: lik at t=167
{
    __shared__ float hn_lds[128 * 65];  // padded stride 65 -> conflict-free
    const int cid = blockIdx.x * 128 + threadIdx.x;   // cid = n*168 + t
    const int n = cid / SEQ;
    const int t = cid - n * SEQ;

    const float yv = y[cid];

    float h[64];
    {
        const float4* xp = (const float4*)(X + (size_t)cid * F_INP);
        #pragma unroll
        for (int q = 0; q < 8; ++q) {
            float4 v = xp[q];
            h[4*q+0] = v.x; h[4*q+1] = v.y; h[4*q+2] = v.z; h[4*q+3] = v.w;
        }
        #pragma unroll
        for (int e = 0; e < 32; ++e)
            h[32 + e] = fmaf(yv, W_embed[e], b_embed[e]);
    }

    float* myh = hn_lds + threadIdx.x * 65;

    #pragma unroll 1
    for (int l = 0; l < 2; ++l) {
        const float* W  = W_ih + l * 256 * 64;
        const float* bi = b_ih + l * 256;
        const float* bh = b_hh + l * 256;
        #pragma unroll 1
        for (int j = 0; j < 64; ++j) {
            const float* wi = W + j * 64;            // i-gate row
            const float* wg = W + (128 + j) * 64;    // g-gate row
            const float* wo = W + (192 + j) * 64;    // o-gate row
            float ai = bi[j]       + bh[j];
            float ag = bi[128 + j] + bh[128 + j];
            float ao = bi[192 + j] + bh[192 + j];
            #pragma unroll
            for (int k = 0; k < 64; ++k) {
                const float hk = h[k];
                ai = fmaf(hk, wi[k], ai);
                ag = fmaf(hk, wg[k], ag);
                ao = fmaf(hk, wo[k], ao);
            }
            const float c = sigm(ai) * tanh_(ag);
            myh[j] = sigm(ao) * tanh_(c);
        }
        #pragma unroll
        for (int k = 0; k < 64; ++k) h[k] = myh[k];  // own slab: no barrier needed
    }

    // heads on relu(h)
    float am = b_mu[0], as = b_sigma[0];
    #pragma unroll
    for (int k = 0; k < 64; ++k) {
        const float hr = fmaxf(h[k], 0.0f);
        am = fmaf(hr, W_mu[k], am);
        as = fmaf(hr, W_sigma[k], as);
    }
    const float sg = softplus_(as) + 1e-6f;
    const float d  = yv - am;
    const float is = frcp(sg);
    const float lik = 0.39894228040143267f * is * fexp(-0.5f * d * d * is * is);

    float* mu_out = out + (size_t)N_TS * HOR;
    float* sg_out = mu_out + (size_t)N_TS * T_ALL;
    mu_out[(size_t)n * T_ALL + t] = am;
    sg_out[(size_t)n * T_ALL + t] = sg;
    if (t == SEQ - 1) {
        out[(size_t)n * HOR + 0] = lik;   // ypred[:,0] = lik at t=167
        lik167[n] = lik;
    }
}

// ---------------------------------------------------------------------------
// Kernel B: autoregressive region t in [168, 192). One block per series.
// 192 threads each own one compacted gate row (both layers) in registers.
// h exchanged via tiny LDS; carry (lik) via LDS scalar.
// ---------------------------------------------------------------------------
__global__ __launch_bounds__(256) void cellsB(
    const float* __restrict__ Xf,       // (N, 24, 32)
    const float* __restrict__ W_embed,
    const float* __restrict__ b_embed,
    const float* __restrict__ W_ih,
    const float* __restrict__ b_ih,
    const float* __restrict__ b_hh,
    const float* __restrict__ W_mu,
    const float* __restrict__ b_mu,
    const float* __restrict__ W_sigma,
    const float* __restrict__ b_sigma,
    float* __restrict__ out,
    const float* __restrict__ lik167)
{
    __shared__ __align__(16) float h_lds[64];
    __shared__ float gacc[192];
    __shared__ float carry_lds;

    const int n   = blockIdx.x;
    const int tid = threadIdx.x;
    const int j    = tid & 63;
    const int gate = tid >> 6;          // 0:i 1:g 2:o 3:idle (wave-uniform)

    float w0[64], w1[64];
    float bsum0 = 0.0f, bsum1 = 0.0f;
    if (gate < 3) {
        const int row = j + (gate == 0 ? 0 : (gate == 1 ? 128 : 192));
        const float* r0 = W_ih + row * 64;
        const float* r1 = W_ih + 256 * 64 + row * 64;
        #pragma unroll
        for (int k = 0; k < 64; ++k) { w0[k] = r0[k]; w1[k] = r1[k]; }
        bsum0 = b_ih[row]       + b_hh[row];
        bsum1 = b_ih[256 + row] + b_hh[256 + row];
    }

    float we = 0.0f, be = 0.0f, wmu = 0.0f, wsg = 0.0f;
    if (tid >= 32 && tid < 64) { we = W_embed[tid - 32]; be = b_embed[tid - 32]; }
    if (tid < 64)              { wmu = W_mu[tid]; wsg = W_sigma[tid]; }
    const float bmu = b_mu[0], bsg = b_sigma[0];

    float ynext = lik167[n];

    float* mu_out = out + (size_t)N_TS * HOR;
    float* sg_out = mu_out + (size_t)N_TS * T_ALL;

    for (int s = 0; s < HOR; ++s) {     // t = 168 + s
        // --- init h ---
        if (tid < 32)       h_lds[tid] = Xf[((size_t)n * HOR + s) * F_INP + tid];
        else if (tid < 64)  h_lds[tid] = fmaf(ynext, we, be);
        __syncthreads();

        // --- layer 1 ---
        if (gate < 3) {
            float a = bsum0;
            const float4* h4 = (const float4*)h_lds;
            #pragma unroll
            for (int q = 0; q < 16; ++q) {
                float4 hv = h4[q];
                a = fmaf(hv.x, w0[4*q+0], a);
                a = fmaf(hv.y, w0[4*q+1], a);
                a = fmaf(hv.z, w0[4*q+2], a);
                a = fmaf(hv.w, w0[4*q+3], a);
            }
            gacc[tid] = a;
        }
        __syncthreads();
        if (tid < 64) {
            const float c = sigm(gacc[tid]) * tanh_(gacc[64 + tid]);
            h_lds[tid] = sigm(gacc[128 + tid]) * tanh_(c);
        }
        __syncthreads();

        // --- layer 2 ---
        if (gate < 3) {
            float a = bsum1;
            const float4* h4 = (const float4*)h_lds;
            #pragma unroll
            for (int q = 0; q < 16; ++q) {
                float4 hv = h4[q];
                a = fmaf(hv.x, w1[4*q+0], a);
                a = fmaf(hv.y, w1[4*q+1], a);
                a = fmaf(hv.z, w1[4*q+2], a);
                a = fmaf(hv.w, w1[4*q+3], a);
            }
            gacc[tid] = a;
        }
        __syncthreads();
        if (tid < 64) {
            const float c = sigm(gacc[tid]) * tanh_(gacc[64 + tid]);
            h_lds[tid] = sigm(gacc[128 + tid]) * tanh_(c);
        }
        __syncthreads();

        // --- heads (wave 0) ---
        if (tid < 64) {
            const float hr = fmaxf(h_lds[tid], 0.0f);
            float pm = hr * wmu;
            float ps = hr * wsg;
            #pragma unroll
            for (int off = 32; off; off >>= 1) {
                pm += __shfl_down(pm, off, 64);
                ps += __shfl_down(ps, off, 64);
            }
            if (tid == 0) {
                const float mu = pm + bmu;
                const float sg = softplus_(ps + bsg) + 1e-6f;
                const float d  = ynext - mu;
                const float is = frcp(sg);
                const float lik = 0.39894228040143267f * is * fexp(-0.5f * d * d * is * is);
                const int t = SEQ + s;
                mu_out[(size_t)n * T_ALL + t] = mu;
                sg_out[(size_t)n * T_ALL + t] = sg;
                if (s < HOR - 1) out[(size_t)n * HOR + (s + 1)] = lik;
                carry_lds = lik;
            }
        }
        __syncthreads();
        ynext = carry_lds;
    }
}

extern "C" void kernel_launch(void* const* d_in, const int* in_sizes, int n_in,
                              void* d_out, int out_size, void* d_ws, size_t ws_size,
                              hipStream_t stream) {
    const float* X       = (const float*)d_in[0];
    const float* y       = (const float*)d_in[1];
    const float* Xf      = (const float*)d_in[2];
    const float* W_embed = (const float*)d_in[3];
    const float* b_embed = (const float*)d_in[4];
    const float* W_ih    = (const float*)d_in[5];
    const float* b_ih    = (const float*)d_in[6];
    const float* b_hh    = (const float*)d_in[7];
    const float* W_mu    = (const float*)d_in[8];
    const float* b_mu    = (const float*)d_in[9];
    const float* W_sigma = (const float*)d_in[10];
    const float* b_sigma = (const float*)d_in[11];

    float* out    = (float*)d_out;
    float* lik167 = (float*)d_ws;   // 4096 floats

    const int cellsA_count = N_TS * SEQ;           // 688128
    cellsA<<<cellsA_count / 128, 128, 0, stream>>>(
        X, y, W_embed, b_embed, W_ih, b_ih, b_hh,
        W_mu, b_mu, W_sigma, b_sigma, out, lik167);

    cellsB<<<N_TS, 256, 0, stream>>>(
        Xf, W_embed, b_embed, W_ih, b_ih, b_hh,
        W_mu, b_mu, W_sigma, b_sigma, out, lik167);
}

// Round 2
// 416.368 us; speedup vs baseline: 3.0063x; 3.0063x over previous
//
#include <hip/hip_runtime.h>
#include <math.h>

#define N_TS 4096
#define SEQ  168
#define HOR  24
#define T_ALL 192
#define F_INP 32
#define HID  64
#define NROW 192           // compacted gate rows: i(64) g(64) o(64)
#define HPAD 72            // padded fp16 row stride (144 B: 16B-aligned, 2-way-bank-free)

typedef _Float16 half8  __attribute__((ext_vector_type(8)));
typedef float    floatx4 __attribute__((ext_vector_type(4)));

__device__ __forceinline__ float fexp(float x)  { return __expf(x); }
__device__ __forceinline__ float frcp(float x)  { return __builtin_amdgcn_rcpf(x); }
__device__ __forceinline__ float sigm(float x)  { return frcp(1.0f + fexp(-x)); }
__device__ __forceinline__ float tanh_(float x) { return 1.0f - 2.0f * frcp(1.0f + fexp(2.0f * x)); }
__device__ __forceinline__ float softplus_(float x) { return (x > 15.0f) ? x : __logf(1.0f + fexp(x)); }

// ---------------------------------------------------------------------------
// prep: compact weights (drop dead f-gate), convert to fp16, fuse biases.
// W16[l][row][k], row order i(0..63) g(64..127) o(128..191); bsum[l][row].
// ---------------------------------------------------------------------------
__global__ __launch_bounds__(256) void prep(
    const float* __restrict__ W_ih, const float* __restrict__ b_ih,
    const float* __restrict__ b_hh,
    _Float16* __restrict__ W16, float* __restrict__ bsum)
{
    const int idx = blockIdx.x * 256 + threadIdx.x;
    for (int i = idx; i < 2 * NROW * HID; i += gridDim.x * 256) {
        const int k = i & 63;
        const int r = (i >> 6) % NROW;
        const int l = i / (NROW * HID);
        const int sr = (r < 64) ? r : r + 64;     // skip f rows 64..127
        W16[i] = (_Float16)W_ih[(l * 256 + sr) * HID + k];
    }
    for (int i = idx; i < 2 * NROW; i += gridDim.x * 256) {
        const int r = i % NROW;
        const int l = i / NROW;
        const int sr = (r < 64) ? r : r + 64;
        bsum[i] = b_ih[l * 256 + sr] + b_hh[l * 256 + sr];
    }
}

// ---------------------------------------------------------------------------
// cellsA: teacher-forced region. 128 cells/block, 4 waves x 32 cells.
// MFMA 16x16x32 f16: A = cells x k (LDS, padded), B = W16 rows (global, cached).
// No __syncthreads: each wave stages and consumes only its own 32 H rows.
// ---------------------------------------------------------------------------
__global__ __launch_bounds__(256, 2) void cellsA(
    const float* __restrict__ X,
    const float* __restrict__ y,
    const float* __restrict__ W_embed,
    const float* __restrict__ b_embed,
    const _Float16* __restrict__ W16,
    const float* __restrict__ bsum,
    const float* __restrict__ W_mu,
    const float* __restrict__ b_mu,
    const float* __restrict__ W_sigma,
    const float* __restrict__ b_sigma,
    float* __restrict__ out,
    float* __restrict__ lik167)
{
    __shared__ __align__(16) _Float16 Hs[128 * HPAD];   // 18432 B
    const int tid   = threadIdx.x;
    const int w     = tid >> 6;
    const int lane  = tid & 63;
    const int quad  = lane >> 4;
    const int ln    = lane & 15;
    const int cell0 = w * 32;

    // ---- stage H0 for this wave's 32 cells ----
    {
        const int cl  = cell0 + (lane & 31);
        const int cid = blockIdx.x * 128 + cl;
        _Float16* row = Hs + cl * HPAD;
        if (lane < 32) {
            const float4* xp = (const float4*)(X + (size_t)cid * F_INP);
            #pragma unroll
            for (int c = 0; c < 4; ++c) {
                const float4 a = xp[2 * c];
                const float4 b = xp[2 * c + 1];
                half8 v;
                v[0]=(_Float16)a.x; v[1]=(_Float16)a.y; v[2]=(_Float16)a.z; v[3]=(_Float16)a.w;
                v[4]=(_Float16)b.x; v[5]=(_Float16)b.y; v[6]=(_Float16)b.z; v[7]=(_Float16)b.w;
                *(half8*)(row + c * 8) = v;
            }
        } else {
            const float yv = y[cid];
            #pragma unroll
            for (int c = 0; c < 4; ++c) {
                half8 v;
                #pragma unroll
                for (int e = 0; e < 8; ++e)
                    v[e] = (_Float16)fmaf(yv, W_embed[c * 8 + e], b_embed[c * 8 + e]);
                *(half8*)(row + 32 + c * 8) = v;
            }
        }
    }

    float hfin[2][4][4];   // [mt][jt][reg] layer-2 h (fp32)

    #pragma unroll
    for (int l = 0; l < 2; ++l) {
        // A fragments: A[m=ln][k=quad*8+j] -> 16B contiguous per lane
        half8 afr[2][2];
        #pragma unroll
        for (int mt = 0; mt < 2; ++mt)
            #pragma unroll
            for (int kt = 0; kt < 2; ++kt)
                afr[mt][kt] = *(const half8*)(Hs + (cell0 + mt * 16 + ln) * HPAD + kt * 32 + quad * 8);

        float bias[12];
        #pragma unroll
        for (int nt = 0; nt < 12; ++nt)
            bias[nt] = bsum[l * NROW + nt * 16 + ln];

        floatx4 acc[2][12];
        #pragma unroll
        for (int mt = 0; mt < 2; ++mt)
            #pragma unroll
            for (int nt = 0; nt < 12; ++nt)
                acc[mt][nt] = (floatx4){0.f, 0.f, 0.f, 0.f};

        const _Float16* bp = W16 + (size_t)l * NROW * HID + ln * HID + quad * 8;
        #pragma unroll
        for (int nt = 0; nt < 12; ++nt) {
            const half8 b0 = *(const half8*)(bp + nt * 16 * HID);
            const half8 b1 = *(const half8*)(bp + nt * 16 * HID + 32);
            #pragma unroll
            for (int mt = 0; mt < 2; ++mt) {
                acc[mt][nt] = __builtin_amdgcn_mfma_f32_16x16x32_f16(afr[mt][0], b0, acc[mt][nt], 0, 0, 0);
                acc[mt][nt] = __builtin_amdgcn_mfma_f32_16x16x32_f16(afr[mt][1], b1, acc[mt][nt], 0, 0, 0);
            }
        }

        // activation: i/g/o for unit j=jt*16+ln live in tiles jt, 4+jt, 8+jt at same lane/reg
        #pragma unroll
        for (int mt = 0; mt < 2; ++mt)
        #pragma unroll
        for (int jt = 0; jt < 4; ++jt)
        #pragma unroll
        for (int r = 0; r < 4; ++r) {
            const float ig = acc[mt][jt][r]     + bias[jt];
            const float gg = acc[mt][4 + jt][r] + bias[4 + jt];
            const float og = acc[mt][8 + jt][r] + bias[8 + jt];
            const float cc = sigm(ig) * tanh_(gg);
            const float hh = sigm(og) * tanh_(cc);
            if (l == 0)
                Hs[(cell0 + mt * 16 + quad * 4 + r) * HPAD + jt * 16 + ln] = (_Float16)hh;
            else
                hfin[mt][jt][r] = hh;
        }
    }

    // ---- heads ----
    float wmu[4], wsg[4];
    #pragma unroll
    for (int jt = 0; jt < 4; ++jt) {
        wmu[jt] = W_mu[jt * 16 + ln];
        wsg[jt] = W_sigma[jt * 16 + ln];
    }
    const float bmu = b_mu[0], bsg = b_sigma[0];
    float* mu_out = out + (size_t)N_TS * HOR;
    float* sg_out = mu_out + (size_t)N_TS * T_ALL;

    #pragma unroll
    for (int mt = 0; mt < 2; ++mt)
    #pragma unroll
    for (int r = 0; r < 4; ++r) {
        float pm = 0.f, ps = 0.f;
        #pragma unroll
        for (int jt = 0; jt < 4; ++jt) {
            const float hr = fmaxf(hfin[mt][jt][r], 0.f);
            pm = fmaf(hr, wmu[jt], pm);
            ps = fmaf(hr, wsg[jt], ps);
        }
        #pragma unroll
        for (int off = 1; off < 16; off <<= 1) {
            pm += __shfl_xor(pm, off, 64);
            ps += __shfl_xor(ps, off, 64);
        }
        if (ln == 0) {
            const int cl  = cell0 + mt * 16 + quad * 4 + r;
            const int cid = blockIdx.x * 128 + cl;
            const int n = cid / SEQ;
            const int t = cid - n * SEQ;
            const float mu = pm + bmu;
            const float sg = softplus_(ps + bsg) + 1e-6f;
            mu_out[(size_t)n * T_ALL + t] = mu;
            sg_out[(size_t)n * T_ALL + t] = sg;
            if (t == SEQ - 1) {
                const float yv = y[cid];
                const float d  = yv - mu;
                const float is = frcp(sg);
                const float lik = 0.39894228040143267f * is * fexp(-0.5f * d * d * is * is);
                out[(size_t)n * HOR] = lik;
                lik167[n] = lik;
            }
        }
    }
}

// ---------------------------------------------------------------------------
// cellsB: autoregressive region. One WAVE per block, 16 series, 24 sequential
// steps. Weights resident in LDS across steps. No barriers (single wave).
// ---------------------------------------------------------------------------
__global__ __launch_bounds__(64, 1) void cellsB(
    const float* __restrict__ Xf,
    const float* __restrict__ W_embed,
    const float* __restrict__ b_embed,
    const _Float16* __restrict__ W16,
    const float* __restrict__ bsum,
    const float* __restrict__ W_mu,
    const float* __restrict__ b_mu,
    const float* __restrict__ W_sigma,
    const float* __restrict__ b_sigma,
    float* __restrict__ out,
    const float* __restrict__ lik167)
{
    __shared__ __align__(16) _Float16 Wl[2 * NROW * HPAD]; // 55296 B
    __shared__ __align__(16) _Float16 Hs[16 * HPAD];       // 2304 B
    __shared__ float ylds[16];

    const int lane = threadIdx.x;
    const int quad = lane >> 4;
    const int ln   = lane & 15;
    const int n0   = blockIdx.x * 16;

    // stage weights into padded LDS (once; reused for 24 steps)
    for (int r = lane; r < 2 * NROW; r += 64) {
        const _Float16* src = W16 + r * HID;
        _Float16* dst = Wl + r * HPAD;
        #pragma unroll
        for (int c = 0; c < 8; ++c)
            *(half8*)(dst + c * 8) = *(const half8*)(src + c * 8);
    }
    if (lane < 16) ylds[lane] = lik167[n0 + lane];

    float bias[2][12];
    #pragma unroll
    for (int l = 0; l < 2; ++l)
        #pragma unroll
        for (int nt = 0; nt < 12; ++nt)
            bias[l][nt] = bsum[l * NROW + nt * 16 + ln];

    float wmu[4], wsg[4];
    #pragma unroll
    for (int jt = 0; jt < 4; ++jt) {
        wmu[jt] = W_mu[jt * 16 + ln];
        wsg[jt] = W_sigma[jt * 16 + ln];
    }
    const float bmu = b_mu[0], bsg = b_sigma[0];

    // embed constants for staging lanes (quads 2,3 cover k=32..63)
    float we[16], be[16];
    if (quad >= 2) {
        const int ks = (quad - 2) * 16;
        #pragma unroll
        for (int e = 0; e < 16; ++e) {
            we[e] = W_embed[ks + e];
            be[e] = b_embed[ks + e];
        }
    }

    float* mu_out = out + (size_t)N_TS * HOR;
    float* sg_out = mu_out + (size_t)N_TS * T_ALL;
    const int sr = ln;   // series staged by this lane

    for (int s = 0; s < HOR; ++s) {
        // ---- stage H (16 series x 64 k; 4 lanes per series) ----
        if (quad < 2) {
            const float4* xp = (const float4*)(Xf + ((size_t)(n0 + sr) * HOR + s) * F_INP + quad * 16);
            _Float16* row = Hs + sr * HPAD + quad * 16;
            #pragma unroll
            for (int c = 0; c < 2; ++c) {
                const float4 a = xp[2 * c];
                const float4 b = xp[2 * c + 1];
                half8 v;
                v[0]=(_Float16)a.x; v[1]=(_Float16)a.y; v[2]=(_Float16)a.z; v[3]=(_Float16)a.w;
                v[4]=(_Float16)b.x; v[5]=(_Float16)b.y; v[6]=(_Float16)b.z; v[7]=(_Float16)b.w;
                *(half8*)(row + c * 8) = v;
            }
        } else {
            const float yn = ylds[sr];
            _Float16* row = Hs + sr * HPAD + 32 + (quad - 2) * 16;
            #pragma unroll
            for (int c = 0; c < 2; ++c) {
                half8 v;
                #pragma unroll
                for (int e = 0; e < 8; ++e)
                    v[e] = (_Float16)fmaf(yn, we[c * 8 + e], be[c * 8 + e]);
                *(half8*)(row + c * 8) = v;
            }
        }

        float hfin[4][4];
        #pragma unroll
        for (int l = 0; l < 2; ++l) {
            const half8 a0 = *(const half8*)(Hs + ln * HPAD + quad * 8);
            const half8 a1 = *(const half8*)(Hs + ln * HPAD + 32 + quad * 8);

            floatx4 acc[12];
            #pragma unroll
            for (int nt = 0; nt < 12; ++nt)
                acc[nt] = (floatx4){0.f, 0.f, 0.f, 0.f};

            const _Float16* bp = Wl + l * NROW * HPAD + ln * HPAD + quad * 8;
            #pragma unroll
            for (int nt = 0; nt < 12; ++nt) {
                const half8 b0 = *(const half8*)(bp + nt * 16 * HPAD);
                const half8 b1 = *(const half8*)(bp + nt * 16 * HPAD + 32);
                acc[nt] = __builtin_amdgcn_mfma_f32_16x16x32_f16(a0, b0, acc[nt], 0, 0, 0);
                acc[nt] = __builtin_amdgcn_mfma_f32_16x16x32_f16(a1, b1, acc[nt], 0, 0, 0);
            }

            #pragma unroll
            for (int jt = 0; jt < 4; ++jt)
            #pragma unroll
            for (int r = 0; r < 4; ++r) {
                const float ig = acc[jt][r]     + bias[l][jt];
                const float gg = acc[4 + jt][r] + bias[l][4 + jt];
                const float og = acc[8 + jt][r] + bias[l][8 + jt];
                const float cc = sigm(ig) * tanh_(gg);
                const float hh = sigm(og) * tanh_(cc);
                if (l == 0)
                    Hs[(quad * 4 + r) * HPAD + jt * 16 + ln] = (_Float16)hh;
                else
                    hfin[jt][r] = hh;
            }
        }

        // ---- heads ----
        #pragma unroll
        for (int r = 0; r < 4; ++r) {
            float pm = 0.f, ps = 0.f;
            #pragma unroll
            for (int jt = 0; jt < 4; ++jt) {
                const float hr = fmaxf(hfin[jt][r], 0.f);
                pm = fmaf(hr, wmu[jt], pm);
                ps = fmaf(hr, wsg[jt], ps);
            }
            #pragma unroll
            for (int off = 1; off < 16; off <<= 1) {
                pm += __shfl_xor(pm, off, 64);
                ps += __shfl_xor(ps, off, 64);
            }
            if (ln == 0) {
                const int series = quad * 4 + r;
                const float yn = ylds[series];
                const float mu = pm + bmu;
                const float sg = softplus_(ps + bsg) + 1e-6f;
                const float d  = yn - mu;
                const float is = frcp(sg);
                const float lik = 0.39894228040143267f * is * fexp(-0.5f * d * d * is * is);
                const int nn = n0 + series;
                const int t  = SEQ + s;
                mu_out[(size_t)nn * T_ALL + t] = mu;
                sg_out[(size_t)nn * T_ALL + t] = sg;
                if (s < HOR - 1) out[(size_t)nn * HOR + s + 1] = lik;
                ylds[series] = lik;
            }
        }
    }
}

extern "C" void kernel_launch(void* const* d_in, const int* in_sizes, int n_in,
                              void* d_out, int out_size, void* d_ws, size_t ws_size,
                              hipStream_t stream) {
    const float* X       = (const float*)d_in[0];
    const float* y       = (const float*)d_in[1];
    const float* Xf      = (const float*)d_in[2];
    const float* W_embed = (const float*)d_in[3];
    const float* b_embed = (const float*)d_in[4];
    const float* W_ih    = (const float*)d_in[5];
    const float* b_ih    = (const float*)d_in[6];
    const float* b_hh    = (const float*)d_in[7];
    const float* W_mu    = (const float*)d_in[8];
    const float* b_mu    = (const float*)d_in[9];
    const float* W_sigma = (const float*)d_in[10];
    const float* b_sigma = (const float*)d_in[11];

    float* out = (float*)d_out;
    // ws layout: lik167 (4096 f32) | W16 (2*192*64 f16) | bsum (384 f32)
    float*     lik167 = (float*)d_ws;
    _Float16*  W16    = (_Float16*)((char*)d_ws + 16384);
    float*     bsum   = (float*)((char*)d_ws + 16384 + 49152);

    prep<<<96, 256, 0, stream>>>(W_ih, b_ih, b_hh, W16, bsum);

    cellsA<<<(N_TS * SEQ) / 128, 256, 0, stream>>>(
        X, y, W_embed, b_embed, W16, bsum,
        W_mu, b_mu, W_sigma, b_sigma, out, lik167);

    cellsB<<<N_TS / 16, 64, 0, stream>>>(
        Xf, W_embed, b_embed, W16, bsum,
        W_mu, b_mu, W_sigma, b_sigma, out, lik167);
}

// Round 3
// 392.386 us; speedup vs baseline: 3.1901x; 1.0611x over previous
//
#include <hip/hip_runtime.h>
#include <math.h>

#define N_TS 4096
#define SEQ  168
#define HOR  24
#define T_ALL 192
#define F_INP 32
#define HID  64
#define NROW 192           // compacted gate rows: i(64) g(64) o(64)
#define HPAD 88            // padded fp16 row stride (176 B, 16B-aligned)
#define BCH  8             // cellsB base-chunk steps

typedef _Float16 half8  __attribute__((ext_vector_type(8)));
typedef _Float16 half2  __attribute__((ext_vector_type(2)));
typedef float    floatx4 __attribute__((ext_vector_type(4)));

__device__ __forceinline__ float fexp(float x)  { return __expf(x); }
__device__ __forceinline__ float frcp(float x)  { return __builtin_amdgcn_rcpf(x); }
__device__ __forceinline__ float sigm(float x)  { return frcp(1.0f + fexp(-x)); }
__device__ __forceinline__ float tanh_(float x) { return 1.0f - 2.0f * frcp(1.0f + fexp(2.0f * x)); }
__device__ __forceinline__ float softplus_(float x) { return (x > 15.0f) ? x : __logf(1.0f + fexp(x)); }

// ---------------------------------------------------------------------------
// prep: compact weights (drop dead f-gate), fp16, fused biases, rank-1 embed
// fold: wy1[r] = W1[r,32:]@W_embed ; b1c[r] = b1[r] + W1[r,32:]@b_embed.
// ---------------------------------------------------------------------------
__global__ __launch_bounds__(256) void prep(
    const float* __restrict__ W_ih, const float* __restrict__ b_ih,
    const float* __restrict__ b_hh,
    const float* __restrict__ W_embed, const float* __restrict__ b_embed,
    _Float16* __restrict__ W16, float* __restrict__ bsum,
    float* __restrict__ wy1, float* __restrict__ b1c)
{
    const int idx = blockIdx.x * 256 + threadIdx.x;
    for (int i = idx; i < 2 * NROW * HID; i += gridDim.x * 256) {
        const int k = i & 63;
        const int r = (i >> 6) % NROW;
        const int l = i / (NROW * HID);
        const int sr = (r < 64) ? r : r + 64;     // skip f rows 64..127
        W16[i] = (_Float16)W_ih[(l * 256 + sr) * HID + k];
    }
    for (int i = idx; i < 2 * NROW; i += gridDim.x * 256) {
        const int r = i % NROW;
        const int l = i / NROW;
        const int sr = (r < 64) ? r : r + 64;
        bsum[i] = b_ih[l * 256 + sr] + b_hh[l * 256 + sr];
    }
    if (idx < NROW) {
        const int sr = (idx < 64) ? idx : idx + 64;
        const float* wrow = W_ih + sr * HID + 32;   // layer 0, cols 32..63
        float s1 = 0.f, s2 = 0.f;
        #pragma unroll
        for (int k = 0; k < 32; ++k) {
            s1 = fmaf(wrow[k], W_embed[k], s1);
            s2 = fmaf(wrow[k], b_embed[k], s2);
        }
        wy1[idx] = s1;
        b1c[idx] = b_ih[sr] + b_hh[sr] + s2;
    }
}

// ---------------------------------------------------------------------------
// cellsA: teacher-forced region. 128 cells/block, 4 waves x 32 cells.
// Weights for the active layer staged in LDS (removes per-nt vmcnt stalls).
// ---------------------------------------------------------------------------
__global__ __launch_bounds__(256, 2) void cellsA(
    const float* __restrict__ X,
    const float* __restrict__ y,
    const float* __restrict__ W_embed,
    const float* __restrict__ b_embed,
    const _Float16* __restrict__ W16,
    const float* __restrict__ bsum,
    const float* __restrict__ W_mu,
    const float* __restrict__ b_mu,
    const float* __restrict__ W_sigma,
    const float* __restrict__ b_sigma,
    float* __restrict__ out,
    float* __restrict__ lik167)
{
    __shared__ __align__(16) _Float16 Hs[128 * HPAD];   // 22528 B
    __shared__ __align__(16) _Float16 Wl[NROW * HPAD];  // 33792 B
    const int tid   = threadIdx.x;
    const int w     = tid >> 6;
    const int lane  = tid & 63;
    const int quad  = lane >> 4;
    const int ln    = lane & 15;
    const int cell0 = w * 32;

    // ---- stage H0 for this wave's 32 cells ----
    {
        const int cl  = cell0 + (lane & 31);
        const int cid = blockIdx.x * 128 + cl;
        _Float16* row = Hs + cl * HPAD;
        if (lane < 32) {
            const float4* xp = (const float4*)(X + (size_t)cid * F_INP);
            #pragma unroll
            for (int c = 0; c < 4; ++c) {
                const float4 a = xp[2 * c];
                const float4 b = xp[2 * c + 1];
                half8 v;
                v[0]=(_Float16)a.x; v[1]=(_Float16)a.y; v[2]=(_Float16)a.z; v[3]=(_Float16)a.w;
                v[4]=(_Float16)b.x; v[5]=(_Float16)b.y; v[6]=(_Float16)b.z; v[7]=(_Float16)b.w;
                *(half8*)(row + c * 8) = v;
            }
        } else {
            const float yv = y[cid];
            #pragma unroll
            for (int c = 0; c < 4; ++c) {
                half8 v;
                #pragma unroll
                for (int e = 0; e < 8; ++e)
                    v[e] = (_Float16)fmaf(yv, W_embed[c * 8 + e], b_embed[c * 8 + e]);
                *(half8*)(row + 32 + c * 8) = v;
            }
        }
    }

    float hfin[2][4][4];   // [mt][jt][reg] layer-2 h (fp32)

    #pragma unroll 1
    for (int l = 0; l < 2; ++l) {
        if (l) __syncthreads();   // all waves done reading layer-0 weights
        // stage this layer's weights: 192 rows x 64 f16
        if (tid < NROW) {
            const _Float16* src = W16 + (size_t)(l * NROW + tid) * HID;
            _Float16* dst = Wl + tid * HPAD;
            #pragma unroll
            for (int c = 0; c < 8; ++c)
                *(half8*)(dst + c * 8) = *(const half8*)(src + c * 8);
        }
        __syncthreads();

        half8 afr[2][2];
        #pragma unroll
        for (int mt = 0; mt < 2; ++mt)
            #pragma unroll
            for (int kt = 0; kt < 2; ++kt)
                afr[mt][kt] = *(const half8*)(Hs + (cell0 + mt * 16 + ln) * HPAD + kt * 32 + quad * 8);

        float bias[12];
        #pragma unroll
        for (int nt = 0; nt < 12; ++nt)
            bias[nt] = bsum[l * NROW + nt * 16 + ln];

        floatx4 acc[2][12];
        #pragma unroll
        for (int mt = 0; mt < 2; ++mt)
            #pragma unroll
            for (int nt = 0; nt < 12; ++nt)
                acc[mt][nt] = (floatx4){0.f, 0.f, 0.f, 0.f};

        const _Float16* bp = Wl + ln * HPAD + quad * 8;
        #pragma unroll
        for (int nt = 0; nt < 12; ++nt) {
            const half8 b0 = *(const half8*)(bp + nt * 16 * HPAD);
            const half8 b1 = *(const half8*)(bp + nt * 16 * HPAD + 32);
            #pragma unroll
            for (int mt = 0; mt < 2; ++mt) {
                acc[mt][nt] = __builtin_amdgcn_mfma_f32_16x16x32_f16(afr[mt][0], b0, acc[mt][nt], 0, 0, 0);
                acc[mt][nt] = __builtin_amdgcn_mfma_f32_16x16x32_f16(afr[mt][1], b1, acc[mt][nt], 0, 0, 0);
            }
        }

        #pragma unroll
        for (int mt = 0; mt < 2; ++mt)
        #pragma unroll
        for (int jt = 0; jt < 4; ++jt)
        #pragma unroll
        for (int r = 0; r < 4; ++r) {
            const float ig = acc[mt][jt][r]     + bias[jt];
            const float gg = acc[mt][4 + jt][r] + bias[4 + jt];
            const float og = acc[mt][8 + jt][r] + bias[8 + jt];
            const float cc = sigm(ig) * tanh_(gg);
            const float hh = sigm(og) * tanh_(cc);
            if (l == 0)
                Hs[(cell0 + mt * 16 + quad * 4 + r) * HPAD + jt * 16 + ln] = (_Float16)hh;
            else
                hfin[mt][jt][r] = hh;
        }
    }

    // ---- heads ----
    float wmu[4], wsg[4];
    #pragma unroll
    for (int jt = 0; jt < 4; ++jt) {
        wmu[jt] = W_mu[jt * 16 + ln];
        wsg[jt] = W_sigma[jt * 16 + ln];
    }
    const float bmu = b_mu[0], bsg = b_sigma[0];
    float* mu_out = out + (size_t)N_TS * HOR;
    float* sg_out = mu_out + (size_t)N_TS * T_ALL;

    #pragma unroll
    for (int mt = 0; mt < 2; ++mt)
    #pragma unroll
    for (int r = 0; r < 4; ++r) {
        float pm = 0.f, ps = 0.f;
        #pragma unroll
        for (int jt = 0; jt < 4; ++jt) {
            const float hr = fmaxf(hfin[mt][jt][r], 0.f);
            pm = fmaf(hr, wmu[jt], pm);
            ps = fmaf(hr, wsg[jt], ps);
        }
        #pragma unroll
        for (int off = 1; off < 16; off <<= 1) {
            pm += __shfl_xor(pm, off, 64);
            ps += __shfl_xor(ps, off, 64);
        }
        if (ln == 0) {
            const int cl  = cell0 + mt * 16 + quad * 4 + r;
            const int cid = blockIdx.x * 128 + cl;
            const int n = cid / SEQ;
            const int t = cid - n * SEQ;
            const float mu = pm + bmu;
            const float sg = softplus_(ps + bsg) + 1e-6f;
            mu_out[(size_t)n * T_ALL + t] = mu;
            sg_out[(size_t)n * T_ALL + t] = sg;
            if (t == SEQ - 1) {
                const float yv = y[cid];
                const float d  = yv - mu;
                const float is = frcp(sg);
                const float lik = 0.39894228040143267f * is * fexp(-0.5f * d * d * is * is);
                out[(size_t)n * HOR] = lik;
                lik167[n] = lik;
            }
        }
    }
}

// ---------------------------------------------------------------------------
// cellsB: autoregressive region. One wave per block, 16 series, 24 steps.
// Rank-1 embed fold: layer-1 gates = base1 (precomputed in 8-step bursts,
// carry-independent, LDS) + wy1[row]*y. Layer-2 weights register-resident.
// No per-step LDS round trip between layers; h1 built directly in A-frags.
// ---------------------------------------------------------------------------
__global__ __launch_bounds__(64, 1) void cellsB(
    const float* __restrict__ Xf,
    const _Float16* __restrict__ W16,
    const float* __restrict__ bsum,
    const float* __restrict__ wy1,
    const float* __restrict__ b1c,
    const float* __restrict__ W_mu,
    const float* __restrict__ b_mu,
    const float* __restrict__ W_sigma,
    const float* __restrict__ b_sigma,
    float* __restrict__ out,
    const float* __restrict__ lik167)
{
    __shared__ __align__(16) _Float16 base_lds[BCH][16][200];  // 51200 B
    __shared__ float ylds[16];

    const int lane = threadIdx.x;
    const int quad = lane >> 4;
    const int ln   = lane & 15;
    const int n0   = blockIdx.x * 16;

    // ---- persistent registers ----
    half8 B1[12];         // layer-1 weights, k<32 (A-operand frags for bursts)
    half8 B2[12][2];      // layer-2 weights (B-operand frags)
    #pragma unroll
    for (int nt = 0; nt < 12; ++nt) {
        B1[nt] = *(const half8*)(W16 + (nt * 16 + ln) * HID + quad * 8);
        #pragma unroll
        for (int kt = 0; kt < 2; ++kt)
            B2[nt][kt] = *(const half8*)(W16 + NROW * HID + (nt * 16 + ln) * HID + kt * 32 + quad * 8);
    }
    float4 wyv[3][2][2];  // wy1[g*64 + kt*32 + quad*8 + (0..7)]
    #pragma unroll
    for (int g = 0; g < 3; ++g)
        #pragma unroll
        for (int kt = 0; kt < 2; ++kt) {
            wyv[g][kt][0] = *(const float4*)(wy1 + g * 64 + kt * 32 + quad * 8);
            wyv[g][kt][1] = *(const float4*)(wy1 + g * 64 + kt * 32 + quad * 8 + 4);
        }
    float4 b1cv[12];      // b1c[nt*16 + quad*4 + (0..3)] (burst C layout)
    #pragma unroll
    for (int nt = 0; nt < 12; ++nt)
        b1cv[nt] = *(const float4*)(b1c + nt * 16 + quad * 4);
    float bias2[12];
    #pragma unroll
    for (int nt = 0; nt < 12; ++nt)
        bias2[nt] = bsum[NROW + nt * 16 + ln];
    float wmu[4], wsg[4];
    #pragma unroll
    for (int jt = 0; jt < 4; ++jt) {
        wmu[jt] = W_mu[jt * 16 + ln];
        wsg[jt] = W_sigma[jt * 16 + ln];
    }
    const float bmu = b_mu[0], bsg = b_sigma[0];

    if (lane < 16) ylds[lane] = lik167[n0 + lane];

    float* mu_out = out + (size_t)N_TS * HOR;
    float* sg_out = mu_out + (size_t)N_TS * T_ALL;

    #pragma unroll 1
    for (int chunk = 0; chunk < HOR / BCH; ++chunk) {
        const int s0 = chunk * BCH;

        // ---- burst: base1 for steps s0..s0+7 (carry-independent) ----
        // C^T form: A = W1 row-tile, B = x^T  ->  C[row=unit, col=series=ln]
        #pragma unroll
        for (int sl = 0; sl < BCH; ++sl) {
            const float* xp = Xf + ((size_t)(n0 + ln) * HOR + s0 + sl) * F_INP + quad * 8;
            const float4 xa = *(const float4*)xp;
            const float4 xb = *(const float4*)(xp + 4);
            half8 xf;
            xf[0]=(_Float16)xa.x; xf[1]=(_Float16)xa.y; xf[2]=(_Float16)xa.z; xf[3]=(_Float16)xa.w;
            xf[4]=(_Float16)xb.x; xf[5]=(_Float16)xb.y; xf[6]=(_Float16)xb.z; xf[7]=(_Float16)xb.w;
            #pragma unroll
            for (int nt = 0; nt < 12; ++nt) {
                floatx4 a = (floatx4){0.f, 0.f, 0.f, 0.f};
                a = __builtin_amdgcn_mfma_f32_16x16x32_f16(B1[nt], xf, a, 0, 0, 0);
                // write units nt*16+quad*4+{0..3} for series ln, r-pairs packed
                #pragma unroll
                for (int rp = 0; rp < 2; ++rp) {
                    half2 v;
                    v[0] = (_Float16)(a[2 * rp]     + b1cv[nt][2 * rp]);
                    v[1] = (_Float16)(a[2 * rp + 1] + b1cv[nt][2 * rp + 1]);
                    *(half2*)(&base_lds[sl][ln][nt * 16 + quad * 4 + 2 * rp]) = v;
                }
            }
        }

        // ---- sequential steps ----
        #pragma unroll 1
        for (int sl = 0; sl < BCH; ++sl) {
            const int s = s0 + sl;
            const float yn = ylds[ln];

            // layer 1: per-lane scalar rank-1 gates -> h1 straight into A-frags
            half8 afr[2];
            #pragma unroll
            for (int kt = 0; kt < 2; ++kt) {
                const half8 bi = *(const half8*)(&base_lds[sl][ln][kt * 32 + quad * 8]);
                const half8 bg = *(const half8*)(&base_lds[sl][ln][64 + kt * 32 + quad * 8]);
                const half8 bo = *(const half8*)(&base_lds[sl][ln][128 + kt * 32 + quad * 8]);
                #pragma unroll
                for (int e = 0; e < 8; ++e) {
                    const float wi = (e < 4) ? ((const float*)&wyv[0][kt][0])[e] : ((const float*)&wyv[0][kt][1])[e - 4];
                    const float wg = (e < 4) ? ((const float*)&wyv[1][kt][0])[e] : ((const float*)&wyv[1][kt][1])[e - 4];
                    const float wo = (e < 4) ? ((const float*)&wyv[2][kt][0])[e] : ((const float*)&wyv[2][kt][1])[e - 4];
                    const float ig = fmaf(yn, wi, (float)bi[e]);
                    const float gg = fmaf(yn, wg, (float)bg[e]);
                    const float og = fmaf(yn, wo, (float)bo[e]);
                    const float cc = sigm(ig) * tanh_(gg);
                    afr[kt][e] = (_Float16)(sigm(og) * tanh_(cc));
                }
            }

            // layer 2: MFMA with register-resident weights
            floatx4 acc[12];
            #pragma unroll
            for (int nt = 0; nt < 12; ++nt) {
                acc[nt] = (floatx4){0.f, 0.f, 0.f, 0.f};
                acc[nt] = __builtin_amdgcn_mfma_f32_16x16x32_f16(afr[0], B2[nt][0], acc[nt], 0, 0, 0);
                acc[nt] = __builtin_amdgcn_mfma_f32_16x16x32_f16(afr[1], B2[nt][1], acc[nt], 0, 0, 0);
            }

            float hfin[4][4];
            #pragma unroll
            for (int jt = 0; jt < 4; ++jt)
            #pragma unroll
            for (int r = 0; r < 4; ++r) {
                const float ig = acc[jt][r]     + bias2[jt];
                const float gg = acc[4 + jt][r] + bias2[4 + jt];
                const float og = acc[8 + jt][r] + bias2[8 + jt];
                const float cc = sigm(ig) * tanh_(gg);
                hfin[jt][r] = sigm(og) * tanh_(cc);
            }

            // heads: reduce over ln (units), series = quad*4+r
            #pragma unroll
            for (int r = 0; r < 4; ++r) {
                float pm = 0.f, ps = 0.f;
                #pragma unroll
                for (int jt = 0; jt < 4; ++jt) {
                    const float hr = fmaxf(hfin[jt][r], 0.f);
                    pm = fmaf(hr, wmu[jt], pm);
                    ps = fmaf(hr, wsg[jt], ps);
                }
                #pragma unroll
                for (int off = 1; off < 16; off <<= 1) {
                    pm += __shfl_xor(pm, off, 64);
                    ps += __shfl_xor(ps, off, 64);
                }
                if (ln == 0) {
                    const int series = quad * 4 + r;
                    const float yv = ylds[series];
                    const float mu = pm + bmu;
                    const float sg = softplus_(ps + bsg) + 1e-6f;
                    const float d  = yv - mu;
                    const float is = frcp(sg);
                    const float lik = 0.39894228040143267f * is * fexp(-0.5f * d * d * is * is);
                    const int nn = n0 + series;
                    const int t  = SEQ + s;
                    mu_out[(size_t)nn * T_ALL + t] = mu;
                    sg_out[(size_t)nn * T_ALL + t] = sg;
                    if (s < HOR - 1) out[(size_t)nn * HOR + s + 1] = lik;
                    ylds[series] = lik;
                }
            }
        }
    }
}

extern "C" void kernel_launch(void* const* d_in, const int* in_sizes, int n_in,
                              void* d_out, int out_size, void* d_ws, size_t ws_size,
                              hipStream_t stream) {
    const float* X       = (const float*)d_in[0];
    const float* y       = (const float*)d_in[1];
    const float* Xf      = (const float*)d_in[2];
    const float* W_embed = (const float*)d_in[3];
    const float* b_embed = (const float*)d_in[4];
    const float* W_ih    = (const float*)d_in[5];
    const float* b_ih    = (const float*)d_in[6];
    const float* b_hh    = (const float*)d_in[7];
    const float* W_mu    = (const float*)d_in[8];
    const float* b_mu    = (const float*)d_in[9];
    const float* W_sigma = (const float*)d_in[10];
    const float* b_sigma = (const float*)d_in[11];

    float* out = (float*)d_out;
    // ws layout: lik167(4096 f32) | W16(2*192*64 f16) | bsum(384 f32) | wy1(192) | b1c(192)
    float*     lik167 = (float*)d_ws;
    _Float16*  W16    = (_Float16*)((char*)d_ws + 16384);
    float*     bsum   = (float*)((char*)d_ws + 16384 + 49152);
    float*     wy1    = (float*)((char*)d_ws + 16384 + 49152 + 1536);
    float*     b1c    = (float*)((char*)d_ws + 16384 + 49152 + 1536 + 768);

    prep<<<96, 256, 0, stream>>>(W_ih, b_ih, b_hh, W_embed, b_embed, W16, bsum, wy1, b1c);

    cellsA<<<(N_TS * SEQ) / 128, 256, 0, stream>>>(
        X, y, W_embed, b_embed, W16, bsum,
        W_mu, b_mu, W_sigma, b_sigma, out, lik167);

    cellsB<<<N_TS / 16, 64, 0, stream>>>(
        Xf, W16, bsum, wy1, b1c,
        W_mu, b_mu, W_sigma, b_sigma, out, lik167);
}

// Round 4
// 313.189 us; speedup vs baseline: 3.9967x; 1.2529x over previous
//
#include <hip/hip_runtime.h>
#include <math.h>

#define N_TS 4096
#define SEQ  168
#define HOR  24
#define T_ALL 192
#define F_INP 32
#define HID  64
#define NROW 192           // compacted gate rows: i(64) g(64) o(64)
#define HPAD 72            // padded fp16 row stride for Hs (144 B, 16B-aligned)
#define BCH2 6             // cellsB chunk steps (4 chunks of 6)

typedef _Float16 half8  __attribute__((ext_vector_type(8)));
typedef _Float16 half4  __attribute__((ext_vector_type(4)));
typedef float    floatx4 __attribute__((ext_vector_type(4)));

__device__ __forceinline__ float fexp(float x)  { return __expf(x); }
__device__ __forceinline__ float frcp(float x)  { return __builtin_amdgcn_rcpf(x); }
__device__ __forceinline__ float softplus_(float x) { return (x > 15.0f) ? x : __logf(1.0f + fexp(x)); }

// Fused LSTM-cell activation (c0=0): h = sigm(o)*tanh(sigm(i)*tanh(g)).
// sigm(a)*tanh(b) = (1-e^{-2b}) * rcp((1+e^{-a})(1+e^{-2b}))  -> 3 trans each,
// 6 transcendentals/unit vs 8 for naive sigm/tanh pairs.
__device__ __forceinline__ float lstm_h(float ig, float gg, float og) {
    const float Ei = fexp(-ig);
    const float Eg = fexp(-2.0f * gg);
    const float cc = (1.0f - Eg) * frcp((1.0f + Ei) * (1.0f + Eg));
    const float Ec = fexp(-2.0f * cc);
    const float Eo = fexp(-og);
    return (1.0f - Ec) * frcp((1.0f + Ec) * (1.0f + Eo));
}

// ---------------------------------------------------------------------------
// prep: compacted (f-gate dropped) weights in k-chunked MFMA-fragment layout:
//   W16f[ ((l*8 + kb)*192 + row)*8 + kp ],  k = kb*8+kp
// so a B-fragment load (lane ln,quad) is 16B contiguous AND consecutive-ln
// coalesced / LDS-bank-clean. Plus fused biases and rank-1 embed fold.
// ---------------------------------------------------------------------------
__global__ __launch_bounds__(256) void prep(
    const float* __restrict__ W_ih, const float* __restrict__ b_ih,
    const float* __restrict__ b_hh,
    const float* __restrict__ W_embed, const float* __restrict__ b_embed,
    _Float16* __restrict__ W16f, float* __restrict__ bsum,
    float* __restrict__ wy1, float* __restrict__ b1c)
{
    const int idx = blockIdx.x * 256 + threadIdx.x;
    for (int i = idx; i < 2 * 8 * NROW * 8; i += gridDim.x * 256) {
        const int kp  = i & 7;
        const int row = (i >> 3) % NROW;
        const int kb  = ((i >> 3) / NROW) & 7;
        const int l   = i / (8 * NROW * 8);
        const int sr  = (row < 64) ? row : row + 64;   // skip dead f rows
        W16f[i] = (_Float16)W_ih[(l * 256 + sr) * HID + kb * 8 + kp];
    }
    for (int i = idx; i < 2 * NROW; i += gridDim.x * 256) {
        const int r = i % NROW;
        const int l = i / NROW;
        const int sr = (r < 64) ? r : r + 64;
        bsum[i] = b_ih[l * 256 + sr] + b_hh[l * 256 + sr];
    }
    if (idx < NROW) {
        const int sr = (idx < 64) ? idx : idx + 64;
        const float* wrow = W_ih + sr * HID + 32;      // layer 0, cols 32..63
        float s1 = 0.f, s2 = 0.f;
        #pragma unroll
        for (int k = 0; k < 32; ++k) {
            s1 = fmaf(wrow[k], W_embed[k], s1);
            s2 = fmaf(wrow[k], b_embed[k], s2);
        }
        wy1[idx] = s1;
        b1c[idx] = b_ih[sr] + b_hh[sr] + s2;
    }
}

// ---------------------------------------------------------------------------
// cellsA: teacher-forced region. 128 cells/block, 4 waves x 32 cells.
// Per-layer weights staged into LDS in k-chunk layout (conflict-free b128).
// ---------------------------------------------------------------------------
__global__ __launch_bounds__(256, 2) void cellsA(
    const float* __restrict__ X,
    const float* __restrict__ y,
    const float* __restrict__ W_embed,
    const float* __restrict__ b_embed,
    const _Float16* __restrict__ W16f,
    const float* __restrict__ bsum,
    const float* __restrict__ W_mu,
    const float* __restrict__ b_mu,
    const float* __restrict__ W_sigma,
    const float* __restrict__ b_sigma,
    float* __restrict__ out,
    float* __restrict__ lik167)
{
    __shared__ __align__(16) _Float16 Hs[128 * HPAD];   // 18432 B
    __shared__ __align__(16) _Float16 Wl[NROW * HID];   // 24576 B, k-chunk layout
    const int tid   = threadIdx.x;
    const int w     = tid >> 6;
    const int lane  = tid & 63;
    const int quad  = lane >> 4;
    const int ln    = lane & 15;
    const int cell0 = w * 32;

    // ---- stage H0 for this wave's 32 cells ----
    {
        const int cl  = cell0 + (lane & 31);
        const int cid = blockIdx.x * 128 + cl;
        _Float16* row = Hs + cl * HPAD;
        if (lane < 32) {
            const float4* xp = (const float4*)(X + (size_t)cid * F_INP);
            #pragma unroll
            for (int c = 0; c < 4; ++c) {
                const float4 a = xp[2 * c];
                const float4 b = xp[2 * c + 1];
                half8 v;
                v[0]=(_Float16)a.x; v[1]=(_Float16)a.y; v[2]=(_Float16)a.z; v[3]=(_Float16)a.w;
                v[4]=(_Float16)b.x; v[5]=(_Float16)b.y; v[6]=(_Float16)b.z; v[7]=(_Float16)b.w;
                *(half8*)(row + c * 8) = v;
            }
        } else {
            const float yv = y[cid];
            #pragma unroll
            for (int c = 0; c < 4; ++c) {
                half8 v;
                #pragma unroll
                for (int e = 0; e < 8; ++e)
                    v[e] = (_Float16)fmaf(yv, W_embed[c * 8 + e], b_embed[c * 8 + e]);
                *(half8*)(row + 32 + c * 8) = v;
            }
        }
    }

    float hfin[2][4][4];   // [mt][jt][reg] layer-2 h (fp32)

    #pragma unroll 1
    for (int l = 0; l < 2; ++l) {
        if (l) __syncthreads();          // waves done reading Wl(l-1)
        #pragma unroll
        for (int c = 0; c < 6; ++c) {    // coalesced: k-chunk layout in & out
            const int off = (c * 256 + tid) * 8;
            *(half8*)(Wl + off) = *(const half8*)(W16f + l * (8 * NROW * 8) + off);
        }
        __syncthreads();

        half8 afr[2][2];
        #pragma unroll
        for (int mt = 0; mt < 2; ++mt)
            #pragma unroll
            for (int kt = 0; kt < 2; ++kt)
                afr[mt][kt] = *(const half8*)(Hs + (cell0 + mt * 16 + ln) * HPAD + kt * 32 + quad * 8);

        float bias[12];
        #pragma unroll
        for (int nt = 0; nt < 12; ++nt)
            bias[nt] = bsum[l * NROW + nt * 16 + ln];

        floatx4 acc[2][12];
        #pragma unroll
        for (int mt = 0; mt < 2; ++mt)
            #pragma unroll
            for (int nt = 0; nt < 12; ++nt)
                acc[mt][nt] = (floatx4){0.f, 0.f, 0.f, 0.f};

        // B-frags from LDS k-chunk layout: bank = ln*4, conflict-free phases
        const _Float16* bp = Wl + quad * (4 * NROW * 8) / 4 + ln * 8;  // quad*1536 + ln*8
        #pragma unroll
        for (int nt = 0; nt < 12; ++nt) {
            const half8 b0 = *(const half8*)(bp + nt * 128);
            const half8 b1 = *(const half8*)(bp + nt * 128 + 4 * NROW * 8);
            #pragma unroll
            for (int mt = 0; mt < 2; ++mt) {
                acc[mt][nt] = __builtin_amdgcn_mfma_f32_16x16x32_f16(afr[mt][0], b0, acc[mt][nt], 0, 0, 0);
                acc[mt][nt] = __builtin_amdgcn_mfma_f32_16x16x32_f16(afr[mt][1], b1, acc[mt][nt], 0, 0, 0);
            }
        }

        #pragma unroll
        for (int mt = 0; mt < 2; ++mt)
        #pragma unroll
        for (int jt = 0; jt < 4; ++jt)
        #pragma unroll
        for (int r = 0; r < 4; ++r) {
            const float hh = lstm_h(acc[mt][jt][r]     + bias[jt],
                                    acc[mt][4 + jt][r] + bias[4 + jt],
                                    acc[mt][8 + jt][r] + bias[8 + jt]);
            if (l == 0)
                Hs[(cell0 + mt * 16 + quad * 4 + r) * HPAD + jt * 16 + ln] = (_Float16)hh;
            else
                hfin[mt][jt][r] = hh;
        }
    }

    // ---- heads ----
    float wmu[4], wsg[4];
    #pragma unroll
    for (int jt = 0; jt < 4; ++jt) {
        wmu[jt] = W_mu[jt * 16 + ln];
        wsg[jt] = W_sigma[jt * 16 + ln];
    }
    const float bmu = b_mu[0], bsg = b_sigma[0];
    float* mu_out = out + (size_t)N_TS * HOR;
    float* sg_out = mu_out + (size_t)N_TS * T_ALL;

    #pragma unroll
    for (int mt = 0; mt < 2; ++mt)
    #pragma unroll
    for (int r = 0; r < 4; ++r) {
        float pm = 0.f, ps = 0.f;
        #pragma unroll
        for (int jt = 0; jt < 4; ++jt) {
            const float hr = fmaxf(hfin[mt][jt][r], 0.0f);
            pm = fmaf(hr, wmu[jt], pm);
            ps = fmaf(hr, wsg[jt], ps);
        }
        #pragma unroll
        for (int off = 1; off < 16; off <<= 1) {
            pm += __shfl_xor(pm, off, 64);
            ps += __shfl_xor(ps, off, 64);
        }
        if (ln == 0) {
            const int cl  = cell0 + mt * 16 + quad * 4 + r;
            const int cid = blockIdx.x * 128 + cl;
            const int n = cid / SEQ;
            const int t = cid - n * SEQ;
            const float mu = pm + bmu;
            const float sg = softplus_(ps + bsg) + 1e-6f;
            mu_out[(size_t)n * T_ALL + t] = mu;
            sg_out[(size_t)n * T_ALL + t] = sg;
            if (t == SEQ - 1) {
                const float yv = y[cid];
                const float d  = yv - mu;
                const float is = frcp(sg);
                const float lik = 0.39894228040143267f * is * fexp(-0.5f * d * d * is * is);
                out[(size_t)n * HOR] = lik;
                lik167[n] = lik;
            }
        }
    }
}

// ---------------------------------------------------------------------------
// cellsB: autoregressive region. 4 waves/block, 16 series, 24 steps.
// Wave w owns h1 units [16w,16w+16) (layer-1, rank-1 in the carry; base kept
// ENTIRELY in registers per 6-step chunk — burst C-layout == sequential lane
// mapping) and gate-tiles {w,4+w,8+w} of layer-2. h1 exchanged via one padded
// LDS tile; heads via wave-butterfly + cross-wave LDS partials. 3 barriers/step.
// ---------------------------------------------------------------------------
__global__ __launch_bounds__(256, 1) void cellsB(
    const float* __restrict__ Xf,
    const _Float16* __restrict__ W16f,
    const float* __restrict__ bsum,
    const float* __restrict__ wy1,
    const float* __restrict__ b1c,
    const float* __restrict__ W_mu,
    const float* __restrict__ b_mu,
    const float* __restrict__ W_sigma,
    const float* __restrict__ b_sigma,
    float* __restrict__ out,
    const float* __restrict__ lik167)
{
    __shared__ __align__(16) _Float16 Hx[16][HPAD];    // h1 exchange, 2304 B
    __shared__ __align__(16) float partm[16][4];
    __shared__ __align__(16) float parts[16][4];
    __shared__ float ylds[16];

    const int tid  = threadIdx.x;
    const int w    = tid >> 6;
    const int lane = tid & 63;
    const int quad = lane >> 4;
    const int ln   = lane & 15;
    const int n0   = blockIdx.x * 16;

    // ---- persistent registers (small!) ----
    half8 B1[3];        // layer-1 A-frags, row-tiles rt = j*4+w (k<32 -> kb=quad)
    half8 B2[3][2];     // layer-2 B-frags
    #pragma unroll
    for (int j = 0; j < 3; ++j) {
        const int rt = j * 4 + w;
        B1[j] = *(const half8*)(W16f + ((size_t)quad * NROW + rt * 16 + ln) * 8);
        #pragma unroll
        for (int kt = 0; kt < 2; ++kt)
            B2[j][kt] = *(const half8*)(W16f + ((size_t)(8 + kt * 4 + quad) * NROW + rt * 16 + ln) * 8);
    }
    float4 wyv[3], b1cv[3];     // unit = w*16 + quad*4 + r
    #pragma unroll
    for (int g = 0; g < 3; ++g) {
        wyv[g]  = *(const float4*)(wy1 + g * 64 + w * 16 + quad * 4);
        b1cv[g] = *(const float4*)(b1c + g * 64 + w * 16 + quad * 4);
    }
    float bias2[3];
    #pragma unroll
    for (int j = 0; j < 3; ++j)
        bias2[j] = bsum[NROW + (j * 4 + w) * 16 + ln];
    const float wmu = W_mu[w * 16 + ln], wsg = W_sigma[w * 16 + ln];
    const float bmu = b_mu[0], bsg = b_sigma[0];

    if (tid < 16) ylds[tid] = lik167[n0 + tid];
    __syncthreads();

    float* mu_out = out + (size_t)N_TS * HOR;
    float* sg_out = mu_out + (size_t)N_TS * T_ALL;

    #pragma unroll 1
    for (int ch = 0; ch < HOR / BCH2; ++ch) {
        const int s0 = ch * BCH2;

        // ---- burst: carry-independent layer-1 base, kept in registers ----
        // C layout: col=ln=series, row=quad*4+r=unit-in-tile — exactly the
        // lane mapping the sequential phase consumes.
        floatx4 base_i[BCH2], base_g[BCH2], base_o[BCH2];
        #pragma unroll
        for (int sl = 0; sl < BCH2; ++sl) {
            const float* xp = Xf + ((size_t)(n0 + ln) * HOR + s0 + sl) * F_INP + quad * 8;
            const float4 xa = *(const float4*)xp;
            const float4 xb = *(const float4*)(xp + 4);
            half8 xf;
            xf[0]=(_Float16)xa.x; xf[1]=(_Float16)xa.y; xf[2]=(_Float16)xa.z; xf[3]=(_Float16)xa.w;
            xf[4]=(_Float16)xb.x; xf[5]=(_Float16)xb.y; xf[6]=(_Float16)xb.z; xf[7]=(_Float16)xb.w;
            floatx4 t0 = (floatx4){0.f,0.f,0.f,0.f};
            floatx4 t1 = (floatx4){0.f,0.f,0.f,0.f};
            floatx4 t2 = (floatx4){0.f,0.f,0.f,0.f};
            t0 = __builtin_amdgcn_mfma_f32_16x16x32_f16(B1[0], xf, t0, 0, 0, 0);
            t1 = __builtin_amdgcn_mfma_f32_16x16x32_f16(B1[1], xf, t1, 0, 0, 0);
            t2 = __builtin_amdgcn_mfma_f32_16x16x32_f16(B1[2], xf, t2, 0, 0, 0);
            #pragma unroll
            for (int r = 0; r < 4; ++r) {
                t0[r] += ((const float*)&b1cv[0])[r];
                t1[r] += ((const float*)&b1cv[1])[r];
                t2[r] += ((const float*)&b1cv[2])[r];
            }
            base_i[sl] = t0; base_g[sl] = t1; base_o[sl] = t2;
        }

        // ---- sequential steps ----
        #pragma unroll
        for (int sl = 0; sl < BCH2; ++sl) {
            const int s = s0 + sl;
            const float yn = ylds[ln];      // carry of series ln

            // layer 1: units w*16+quad*4+{0..3} of series ln
            half4 h1p;
            #pragma unroll
            for (int r = 0; r < 4; ++r) {
                const float ig = fmaf(yn, ((const float*)&wyv[0])[r], base_i[sl][r]);
                const float gg = fmaf(yn, ((const float*)&wyv[1])[r], base_g[sl][r]);
                const float og = fmaf(yn, ((const float*)&wyv[2])[r], base_o[sl][r]);
                h1p[r] = (_Float16)lstm_h(ig, gg, og);
            }
            *(half4*)(&Hx[ln][w * 16 + quad * 4]) = h1p;   // ds_write_b64
            __syncthreads();

            // layer 2: A = h1 (series ln), B = register-resident weights
            const half8 a0 = *(const half8*)(&Hx[ln][quad * 8]);
            const half8 a1 = *(const half8*)(&Hx[ln][32 + quad * 8]);
            floatx4 acc[3];
            #pragma unroll
            for (int j = 0; j < 3; ++j) {
                acc[j] = (floatx4){0.f,0.f,0.f,0.f};
                acc[j] = __builtin_amdgcn_mfma_f32_16x16x32_f16(a0, B2[j][0], acc[j], 0, 0, 0);
                acc[j] = __builtin_amdgcn_mfma_f32_16x16x32_f16(a1, B2[j][1], acc[j], 0, 0, 0);
            }

            // activation + head partials: unit w*16+ln, series quad*4+r
            float pmr[4], psr[4];
            #pragma unroll
            for (int r = 0; r < 4; ++r) {
                const float hh = lstm_h(acc[0][r] + bias2[0],
                                        acc[1][r] + bias2[1],
                                        acc[2][r] + bias2[2]);
                const float hr = fmaxf(hh, 0.0f);
                pmr[r] = hr * wmu;
                psr[r] = hr * wsg;
            }
            #pragma unroll
            for (int off = 1; off < 16; off <<= 1) {
                #pragma unroll
                for (int r = 0; r < 4; ++r) {
                    pmr[r] += __shfl_xor(pmr[r], off, 64);
                    psr[r] += __shfl_xor(psr[r], off, 64);
                }
            }
            if (ln == 0) {
                #pragma unroll
                for (int r = 0; r < 4; ++r) {
                    partm[quad * 4 + r][w] = pmr[r];
                    parts[quad * 4 + r][w] = psr[r];
                }
            }
            __syncthreads();

            if (tid < 16) {     // finalize series tid
                const float4 m4 = *(const float4*)partm[tid];
                const float4 s4 = *(const float4*)parts[tid];
                const float mu = (m4.x + m4.y) + (m4.z + m4.w) + bmu;
                const float sg = softplus_((s4.x + s4.y) + (s4.z + s4.w) + bsg) + 1e-6f;
                const float yv = ylds[tid];
                const float d  = yv - mu;
                const float is = frcp(sg);
                const float lik = 0.39894228040143267f * is * fexp(-0.5f * d * d * is * is);
                const int nn = n0 + tid;
                const int t  = SEQ + s;
                mu_out[(size_t)nn * T_ALL + t] = mu;
                sg_out[(size_t)nn * T_ALL + t] = sg;
                if (s < HOR - 1) out[(size_t)nn * HOR + s + 1] = lik;
                ylds[tid] = lik;
            }
            __syncthreads();
        }
    }
}

extern "C" void kernel_launch(void* const* d_in, const int* in_sizes, int n_in,
                              void* d_out, int out_size, void* d_ws, size_t ws_size,
                              hipStream_t stream) {
    const float* X       = (const float*)d_in[0];
    const float* y       = (const float*)d_in[1];
    const float* Xf      = (const float*)d_in[2];
    const float* W_embed = (const float*)d_in[3];
    const float* b_embed = (const float*)d_in[4];
    const float* W_ih    = (const float*)d_in[5];
    const float* b_ih    = (const float*)d_in[6];
    const float* b_hh    = (const float*)d_in[7];
    const float* W_mu    = (const float*)d_in[8];
    const float* b_mu    = (const float*)d_in[9];
    const float* W_sigma = (const float*)d_in[10];
    const float* b_sigma = (const float*)d_in[11];

    float* out = (float*)d_out;
    // ws: lik167(16384 B) | W16f(49152 B) | bsum(1536 B) | wy1(768 B) | b1c(768 B)
    float*     lik167 = (float*)d_ws;
    _Float16*  W16f   = (_Float16*)((char*)d_ws + 16384);
    float*     bsum   = (float*)((char*)d_ws + 16384 + 49152);
    float*     wy1    = (float*)((char*)d_ws + 16384 + 49152 + 1536);
    float*     b1c    = (float*)((char*)d_ws + 16384 + 49152 + 1536 + 768);

    prep<<<96, 256, 0, stream>>>(W_ih, b_ih, b_hh, W_embed, b_embed, W16f, bsum, wy1, b1c);

    cellsA<<<(N_TS * SEQ) / 128, 256, 0, stream>>>(
        X, y, W_embed, b_embed, W16f, bsum,
        W_mu, b_mu, W_sigma, b_sigma, out, lik167);

    cellsB<<<N_TS / 16, 256, 0, stream>>>(
        Xf, W16f, bsum, wy1, b1c,
        W_mu, b_mu, W_sigma, b_sigma, out, lik167);
}

// Round 5
// 266.948 us; speedup vs baseline: 4.6891x; 1.1732x over previous
//
#include <hip/hip_runtime.h>
#include <math.h>

#define N_TS 4096
#define SEQ  168
#define HOR  24
#define T_ALL 192
#define F_INP 32
#define HID  64
#define NROW 192           // compacted gate rows: i(64) g(64) o(64)
#define HPAD 72            // padded fp16 row stride (144 B, 16B-aligned)

typedef _Float16 half8  __attribute__((ext_vector_type(8)));
typedef _Float16 half4  __attribute__((ext_vector_type(4)));
typedef float    floatx4 __attribute__((ext_vector_type(4)));

__device__ __forceinline__ float fexp(float x)  { return __expf(x); }
__device__ __forceinline__ float frcp(float x)  { return __builtin_amdgcn_rcpf(x); }
__device__ __forceinline__ float softplus_(float x) { return (x > 15.0f) ? x : __logf(1.0f + fexp(x)); }

// Gates arrive PRESCALED (i,o rows x-1; g rows x-2, folded into weights/biases):
// ipre=-i, gpre=-2g, opre=-o.  h = sigm(o)*tanh(sigm(i)*tanh(g)), c0=0.
__device__ __forceinline__ float lstm_h(float ipre, float gpre, float opre) {
    const float Ei = fexp(ipre);
    const float Eg = fexp(gpre);
    const float cc = (1.0f - Eg) * frcp((1.0f + Ei) * (1.0f + Eg));
    const float Ec = fexp(-2.0f * cc);
    const float Eo = fexp(opre);
    return (1.0f - Ec) * frcp((1.0f + Ec) * (1.0f + Eo));
}

__device__ __forceinline__ half8 cvt8(const float4 a, const float4 b) {
    half8 v;
    v[0]=(_Float16)a.x; v[1]=(_Float16)a.y; v[2]=(_Float16)a.z; v[3]=(_Float16)a.w;
    v[4]=(_Float16)b.x; v[5]=(_Float16)b.y; v[6]=(_Float16)b.z; v[7]=(_Float16)b.w;
    return v;
}

// ---------------------------------------------------------------------------
// prep: compacted (f dropped), PRESCALED weights in k-chunked fragment layout
//   W16f[ ((l*8 + kb)*192 + row)*8 + kp ],  k = kb*8+kp
// bsum/wy1/b1c prescaled identically.
// ---------------------------------------------------------------------------
__global__ __launch_bounds__(256) void prep(
    const float* __restrict__ W_ih, const float* __restrict__ b_ih,
    const float* __restrict__ b_hh,
    const float* __restrict__ W_embed, const float* __restrict__ b_embed,
    _Float16* __restrict__ W16f, float* __restrict__ bsum,
    float* __restrict__ wy1, float* __restrict__ b1c)
{
    const int idx = blockIdx.x * 256 + threadIdx.x;
    for (int i = idx; i < 2 * 8 * NROW * 8; i += gridDim.x * 256) {
        const int kp  = i & 7;
        const int row = (i >> 3) % NROW;
        const int kb  = ((i >> 3) / NROW) & 7;
        const int l   = i / (8 * NROW * 8);
        const int sr  = (row < 64) ? row : row + 64;   // skip dead f rows
        const float sc = (row >= 64 && row < 128) ? -2.0f : -1.0f;
        W16f[i] = (_Float16)(W_ih[(l * 256 + sr) * HID + kb * 8 + kp] * sc);
    }
    for (int i = idx; i < 2 * NROW; i += gridDim.x * 256) {
        const int r = i % NROW;
        const int l = i / NROW;
        const int sr = (r < 64) ? r : r + 64;
        const float sc = (r >= 64 && r < 128) ? -2.0f : -1.0f;
        bsum[i] = (b_ih[l * 256 + sr] + b_hh[l * 256 + sr]) * sc;
    }
    if (idx < NROW) {
        const int sr = (idx < 64) ? idx : idx + 64;
        const float sc = (idx >= 64 && idx < 128) ? -2.0f : -1.0f;
        const float* wrow = W_ih + sr * HID + 32;      // layer 0, cols 32..63
        float s1 = 0.f, s2 = 0.f;
        #pragma unroll
        for (int k = 0; k < 32; ++k) {
            s1 = fmaf(wrow[k], W_embed[k], s1);
            s2 = fmaf(wrow[k], b_embed[k], s2);
        }
        wy1[idx] = s1 * sc;
        b1c[idx] = (b_ih[sr] + b_hh[sr] + s2) * sc;
    }
}

// ---------------------------------------------------------------------------
// cellsA: teacher-forced region. 16 cells/wave, 4 waves/block (64 cells).
// Layer-0 A-frags built directly from global (no input staging LDS); weights
// staged per-layer in LDS; bias folded into MFMA C-init; 48-reg accumulator
// -> ~105 live regs -> 4 waves/SIMD.
// ---------------------------------------------------------------------------
__global__ __launch_bounds__(256, 4) void cellsA(
    const float* __restrict__ X,
    const float* __restrict__ y,
    const float* __restrict__ W_embed,
    const float* __restrict__ b_embed,
    const _Float16* __restrict__ W16f,
    const float* __restrict__ bsum,
    const float* __restrict__ W_mu,
    const float* __restrict__ b_mu,
    const float* __restrict__ W_sigma,
    const float* __restrict__ b_sigma,
    float* __restrict__ out,
    float* __restrict__ lik167)
{
    __shared__ __align__(16) _Float16 Wl[NROW * HID];     // 24576 B, k-chunk
    __shared__ __align__(16) _Float16 Hx[4][16 * HPAD];   // 9216 B
    const int tid  = threadIdx.x;
    const int w    = tid >> 6;
    const int lane = tid & 63;
    const int quad = lane >> 4;
    const int ln   = lane & 15;
    const int cid0 = blockIdx.x * 64 + w * 16;
    const int cid  = cid0 + ln;

    // ---- layer-0 A-frags straight from global ----
    half8 afr0, afr1;
    {
        const float* xp = X + (size_t)cid * F_INP + quad * 8;
        const float4 xa = *(const float4*)xp;
        const float4 xb = *(const float4*)(xp + 4);
        afr0 = cvt8(xa, xb);
        const float yv = y[cid];
        const float4 wa = *(const float4*)(W_embed + quad * 8);
        const float4 wb = *(const float4*)(W_embed + quad * 8 + 4);
        const float4 ba = *(const float4*)(b_embed + quad * 8);
        const float4 bb = *(const float4*)(b_embed + quad * 8 + 4);
        afr1[0]=(_Float16)fmaf(yv, wa.x, ba.x); afr1[1]=(_Float16)fmaf(yv, wa.y, ba.y);
        afr1[2]=(_Float16)fmaf(yv, wa.z, ba.z); afr1[3]=(_Float16)fmaf(yv, wa.w, ba.w);
        afr1[4]=(_Float16)fmaf(yv, wb.x, bb.x); afr1[5]=(_Float16)fmaf(yv, wb.y, bb.y);
        afr1[6]=(_Float16)fmaf(yv, wb.z, bb.z); afr1[7]=(_Float16)fmaf(yv, wb.w, bb.w);
    }

    // ---- stage layer-0 weights (coalesced, k-chunk in & out) ----
    #pragma unroll
    for (int c = 0; c < 6; ++c) {
        const int off = (c * 256 + tid) * 8;
        *(half8*)(Wl + off) = *(const half8*)(W16f + off);
    }
    __syncthreads();

    _Float16* hrow = Hx[w];
    {
        floatx4 acc[12];
        #pragma unroll
        for (int nt = 0; nt < 12; ++nt) {
            const float bv = bsum[nt * 16 + ln];
            acc[nt] = (floatx4){bv, bv, bv, bv};
        }
        const _Float16* bp = Wl + quad * 1536 + ln * 8;
        #pragma unroll
        for (int nt = 0; nt < 12; ++nt) {
            const half8 b0 = *(const half8*)(bp + nt * 128);
            const half8 b1 = *(const half8*)(bp + nt * 128 + 6144);
            acc[nt] = __builtin_amdgcn_mfma_f32_16x16x32_f16(afr0, b0, acc[nt], 0, 0, 0);
            acc[nt] = __builtin_amdgcn_mfma_f32_16x16x32_f16(afr1, b1, acc[nt], 0, 0, 0);
        }
        #pragma unroll
        for (int jt = 0; jt < 4; ++jt)
        #pragma unroll
        for (int r = 0; r < 4; ++r) {
            const float hh = lstm_h(acc[jt][r], acc[4 + jt][r], acc[8 + jt][r]);
            hrow[(quad * 4 + r) * HPAD + jt * 16 + ln] = (_Float16)hh;
        }
    }
    __syncthreads();   // all waves done reading Wl(layer0)

    // ---- stage layer-1 weights ----
    #pragma unroll
    for (int c = 0; c < 6; ++c) {
        const int off = (c * 256 + tid) * 8;
        *(half8*)(Wl + off) = *(const half8*)(W16f + 12288 + off);
    }
    __syncthreads();

    float hfin[4][4];
    {
        const half8 a0 = *(const half8*)(hrow + ln * HPAD + quad * 8);
        const half8 a1 = *(const half8*)(hrow + ln * HPAD + 32 + quad * 8);
        floatx4 acc[12];
        #pragma unroll
        for (int nt = 0; nt < 12; ++nt) {
            const float bv = bsum[NROW + nt * 16 + ln];
            acc[nt] = (floatx4){bv, bv, bv, bv};
        }
        const _Float16* bp = Wl + quad * 1536 + ln * 8;
        #pragma unroll
        for (int nt = 0; nt < 12; ++nt) {
            const half8 b0 = *(const half8*)(bp + nt * 128);
            const half8 b1 = *(const half8*)(bp + nt * 128 + 6144);
            acc[nt] = __builtin_amdgcn_mfma_f32_16x16x32_f16(a0, b0, acc[nt], 0, 0, 0);
            acc[nt] = __builtin_amdgcn_mfma_f32_16x16x32_f16(a1, b1, acc[nt], 0, 0, 0);
        }
        #pragma unroll
        for (int jt = 0; jt < 4; ++jt)
        #pragma unroll
        for (int r = 0; r < 4; ++r)
            hfin[jt][r] = lstm_h(acc[jt][r], acc[4 + jt][r], acc[8 + jt][r]);
    }

    // ---- heads ----
    float wmu[4], wsg[4];
    #pragma unroll
    for (int jt = 0; jt < 4; ++jt) {
        wmu[jt] = W_mu[jt * 16 + ln];
        wsg[jt] = W_sigma[jt * 16 + ln];
    }
    const float bmu = b_mu[0], bsg = b_sigma[0];
    float* mu_out = out + (size_t)N_TS * HOR;
    float* sg_out = mu_out + (size_t)N_TS * T_ALL;

    #pragma unroll
    for (int r = 0; r < 4; ++r) {
        float pm = 0.f, ps = 0.f;
        #pragma unroll
        for (int jt = 0; jt < 4; ++jt) {
            const float hr = fmaxf(hfin[jt][r], 0.0f);
            pm = fmaf(hr, wmu[jt], pm);
            ps = fmaf(hr, wsg[jt], ps);
        }
        #pragma unroll
        for (int off = 1; off < 16; off <<= 1) {
            pm += __shfl_xor(pm, off, 64);
            ps += __shfl_xor(ps, off, 64);
        }
        if (ln == 0) {
            const int cid2 = cid0 + quad * 4 + r;
            const int n = cid2 / SEQ;
            const int t = cid2 - n * SEQ;
            const float mu = pm + bmu;
            const float sg = softplus_(ps + bsg) + 1e-6f;
            mu_out[(size_t)n * T_ALL + t] = mu;
            sg_out[(size_t)n * T_ALL + t] = sg;
            if (t == SEQ - 1) {
                const float yv = y[cid2];
                const float d  = yv - mu;
                const float is = frcp(sg);
                const float lik = 0.39894228040143267f * is * fexp(-0.5f * d * d * is * is);
                out[(size_t)n * HOR] = lik;
                lik167[n] = lik;
            }
        }
    }
}

// ---------------------------------------------------------------------------
// cellsB: autoregressive region. 4 waves/block, 16 series, 24 steps.
// No burst arrays (no spills): layer-1 base recomputed per step (3 MFMAs,
// carry-independent) with one-step x prefetch. 3 barriers/step.
// ---------------------------------------------------------------------------
__global__ __launch_bounds__(256, 1) void cellsB(
    const float* __restrict__ Xf,
    const _Float16* __restrict__ W16f,
    const float* __restrict__ bsum,
    const float* __restrict__ wy1,
    const float* __restrict__ b1c,
    const float* __restrict__ W_mu,
    const float* __restrict__ b_mu,
    const float* __restrict__ W_sigma,
    const float* __restrict__ b_sigma,
    float* __restrict__ out,
    const float* __restrict__ lik167)
{
    __shared__ __align__(16) _Float16 Hx[16][HPAD];    // 2304 B
    __shared__ __align__(16) float partm[16][4];
    __shared__ __align__(16) float parts[16][4];
    __shared__ float ylds[16];

    const int tid  = threadIdx.x;
    const int w    = tid >> 6;
    const int lane = tid & 63;
    const int quad = lane >> 4;
    const int ln   = lane & 15;
    const int n0   = blockIdx.x * 16;

    // ---- persistent registers ----
    half8 B1[3];        // layer-1 A-frags (W rows, k<32), row-tiles rt=j*4+w
    half8 B2[3][2];     // layer-2 B-frags
    #pragma unroll
    for (int j = 0; j < 3; ++j) {
        const int rt = j * 4 + w;
        B1[j] = *(const half8*)(W16f + ((size_t)quad * NROW + rt * 16 + ln) * 8);
        #pragma unroll
        for (int kt = 0; kt < 2; ++kt)
            B2[j][kt] = *(const half8*)(W16f + 12288 + ((size_t)(kt * 4 + quad) * NROW + rt * 16 + ln) * 8);
    }
    float4 wyv[3], b1cv[3];     // gate-row = g*64 + w*16 + quad*4 + r
    #pragma unroll
    for (int g = 0; g < 3; ++g) {
        wyv[g]  = *(const float4*)(wy1 + g * 64 + w * 16 + quad * 4);
        b1cv[g] = *(const float4*)(b1c + g * 64 + w * 16 + quad * 4);
    }
    float bias2[3];
    #pragma unroll
    for (int j = 0; j < 3; ++j)
        bias2[j] = bsum[NROW + (j * 4 + w) * 16 + ln];
    const float wmu = W_mu[w * 16 + ln], wsg = W_sigma[w * 16 + ln];
    const float bmu = b_mu[0], bsg = b_sigma[0];

    if (tid < 16) ylds[tid] = lik167[n0 + tid];
    __syncthreads();

    float* mu_out = out + (size_t)N_TS * HOR;
    float* sg_out = mu_out + (size_t)N_TS * T_ALL;

    const float* xbase = Xf + (size_t)(n0 + ln) * HOR * F_INP + quad * 8;
    float4 xa = *(const float4*)xbase;
    float4 xb = *(const float4*)(xbase + 4);

    #pragma unroll 1
    for (int s = 0; s < HOR; ++s) {
        const half8 xf = cvt8(xa, xb);
        if (s < HOR - 1) {                 // prefetch next step's x
            xa = *(const float4*)(xbase + (s + 1) * F_INP);
            xb = *(const float4*)(xbase + (s + 1) * F_INP + 4);
        }

        // layer-1 base (carry-independent): C row=gate-row-in-tile, col=series
        floatx4 t0, t1, t2;
        #pragma unroll
        for (int r = 0; r < 4; ++r) {
            t0[r] = ((const float*)&b1cv[0])[r];
            t1[r] = ((const float*)&b1cv[1])[r];
            t2[r] = ((const float*)&b1cv[2])[r];
        }
        t0 = __builtin_amdgcn_mfma_f32_16x16x32_f16(B1[0], xf, t0, 0, 0, 0);
        t1 = __builtin_amdgcn_mfma_f32_16x16x32_f16(B1[1], xf, t1, 0, 0, 0);
        t2 = __builtin_amdgcn_mfma_f32_16x16x32_f16(B1[2], xf, t2, 0, 0, 0);

        const float yn = ylds[ln];
        half4 h1p;
        #pragma unroll
        for (int r = 0; r < 4; ++r) {
            const float ig = fmaf(yn, ((const float*)&wyv[0])[r], t0[r]);
            const float gg = fmaf(yn, ((const float*)&wyv[1])[r], t1[r]);
            const float og = fmaf(yn, ((const float*)&wyv[2])[r], t2[r]);
            h1p[r] = (_Float16)lstm_h(ig, gg, og);
        }
        *(half4*)(&Hx[ln][w * 16 + quad * 4]) = h1p;
        __syncthreads();

        // layer 2: A = h1 (16 series), B = register-resident weights
        const half8 a0 = *(const half8*)(&Hx[ln][quad * 8]);
        const half8 a1 = *(const half8*)(&Hx[ln][32 + quad * 8]);
        floatx4 acc[3];
        #pragma unroll
        for (int j = 0; j < 3; ++j) {
            acc[j] = (floatx4){bias2[j], bias2[j], bias2[j], bias2[j]};
            acc[j] = __builtin_amdgcn_mfma_f32_16x16x32_f16(a0, B2[j][0], acc[j], 0, 0, 0);
            acc[j] = __builtin_amdgcn_mfma_f32_16x16x32_f16(a1, B2[j][1], acc[j], 0, 0, 0);
        }

        // activation + head partials: unit w*16+ln, series quad*4+r
        float pmr[4], psr[4];
        #pragma unroll
        for (int r = 0; r < 4; ++r) {
            const float hh = lstm_h(acc[0][r], acc[1][r], acc[2][r]);
            const float hr = fmaxf(hh, 0.0f);
            pmr[r] = hr * wmu;
            psr[r] = hr * wsg;
        }
        #pragma unroll
        for (int off = 1; off < 16; off <<= 1) {
            #pragma unroll
            for (int r = 0; r < 4; ++r) {
                pmr[r] += __shfl_xor(pmr[r], off, 64);
                psr[r] += __shfl_xor(psr[r], off, 64);
            }
        }
        if (ln == 0) {
            #pragma unroll
            for (int r = 0; r < 4; ++r) {
                partm[quad * 4 + r][w] = pmr[r];
                parts[quad * 4 + r][w] = psr[r];
            }
        }
        __syncthreads();

        if (tid < 16) {     // finalize series tid
            const float4 m4 = *(const float4*)partm[tid];
            const float4 s4 = *(const float4*)parts[tid];
            const float mu = (m4.x + m4.y) + (m4.z + m4.w) + bmu;
            const float sg = softplus_((s4.x + s4.y) + (s4.z + s4.w) + bsg) + 1e-6f;
            const float yv = ylds[tid];
            const float d  = yv - mu;
            const float is = frcp(sg);
            const float lik = 0.39894228040143267f * is * fexp(-0.5f * d * d * is * is);
            const int nn = n0 + tid;
            const int t  = SEQ + s;
            mu_out[(size_t)nn * T_ALL + t] = mu;
            sg_out[(size_t)nn * T_ALL + t] = sg;
            if (s < HOR - 1) out[(size_t)nn * HOR + s + 1] = lik;
            ylds[tid] = lik;
        }
        __syncthreads();
    }
}

extern "C" void kernel_launch(void* const* d_in, const int* in_sizes, int n_in,
                              void* d_out, int out_size, void* d_ws, size_t ws_size,
                              hipStream_t stream) {
    const float* X       = (const float*)d_in[0];
    const float* y       = (const float*)d_in[1];
    const float* Xf      = (const float*)d_in[2];
    const float* W_embed = (const float*)d_in[3];
    const float* b_embed = (const float*)d_in[4];
    const float* W_ih    = (const float*)d_in[5];
    const float* b_ih    = (const float*)d_in[6];
    const float* b_hh    = (const float*)d_in[7];
    const float* W_mu    = (const float*)d_in[8];
    const float* b_mu    = (const float*)d_in[9];
    const float* W_sigma = (const float*)d_in[10];
    const float* b_sigma = (const float*)d_in[11];

    float* out = (float*)d_out;
    // ws: lik167(16384 B) | W16f(49152 B) | bsum(1536 B) | wy1(768 B) | b1c(768 B)
    float*     lik167 = (float*)d_ws;
    _Float16*  W16f   = (_Float16*)((char*)d_ws + 16384);
    float*     bsum   = (float*)((char*)d_ws + 16384 + 49152);
    float*     wy1    = (float*)((char*)d_ws + 16384 + 49152 + 1536);
    float*     b1c    = (float*)((char*)d_ws + 16384 + 49152 + 1536 + 768);

    prep<<<96, 256, 0, stream>>>(W_ih, b_ih, b_hh, W_embed, b_embed, W16f, bsum, wy1, b1c);

    cellsA<<<(N_TS * SEQ) / 64, 256, 0, stream>>>(
        X, y, W_embed, b_embed, W16f, bsum,
        W_mu, b_mu, W_sigma, b_sigma, out, lik167);

    cellsB<<<N_TS / 16, 256, 0, stream>>>(
        Xf, W16f, bsum, wy1, b1c,
        W_mu, b_mu, W_sigma, b_sigma, out, lik167);
}